// Round 9
// baseline (155.453 us; speedup 1.0000x reference)
//
#include <hip/hip_runtime.h>
#include <math.h>

typedef __attribute__((ext_vector_type(8)))  short  short8;
typedef __attribute__((ext_vector_type(16))) float  float16;

#define TWO_PI_OVER_32 0.19634954084936207f

static __device__ __forceinline__ unsigned short f2bf(float f) {
    unsigned int u = __float_as_uint(f);
    u = (u + 0x7FFFu + ((u >> 16) & 1u)) >> 16;
    return (unsigned short)u;
}
static __device__ __forceinline__ float bf2f(unsigned short s) {
    return __uint_as_float(((unsigned int)s) << 16);
}

// async global->LDS 16B: per-lane global src, wave-uniform LDS base + lane*16
static __device__ __forceinline__ void g2l16(const void* g, void* l) {
    __builtin_amdgcn_global_load_lds(
        (const __attribute__((address_space(1))) unsigned int*)g,
        (__attribute__((address_space(3))) unsigned int*)l, 16, 0, 0);
}

// raw barrier + compiler-motion fence (no vmcnt drain, unlike __syncthreads)
#define SBAR() do { __builtin_amdgcn_s_barrier(); \
                    __builtin_amdgcn_sched_barrier(0); } while (0)
// counted vmcnt: retire oldest loads, keep newest N in flight across barriers
#define WAITV(n) do { asm volatile("s_waitcnt vmcnt(" #n ")" ::: "memory"); \
                      __builtin_amdgcn_sched_barrier(0); } while (0)

// ---------------------------------------------------------------------------
// K_prepx:
//  blocks 0..1023: x fp32 -> xb bf16 granules via LDS transpose, vectorized.
//    R9 fix: granule store index g = k*256+tid (coalesced 16B/lane stores;
//    old g = tid*4+k wrote 4 consecutive uint4 per lane = 64B-stride scatter).
//  blocks 1024..1279 (row mode, p): Drow[45][256]; wt bf16 granules; Vb bf16
//  blocks 1280..1535 (col mode, c): Dcol[45][256]
// ---------------------------------------------------------------------------
__global__ __launch_bounds__(256) void k_prepx(const float* __restrict__ x,
                                               unsigned short* __restrict__ xb,
                                               const float* __restrict__ w,
                                               unsigned short* __restrict__ wt,
                                               unsigned short* __restrict__ Vb,
                                               float* __restrict__ Drow,
                                               float* __restrict__ Dcol) {
    __shared__ union {
        unsigned short tr[8 * 1024];             // [u][r*32+c] 16 KB
        struct { float sdata[45]; float ws2[256 * 9]; } wm;
    } sh;
    int tid = threadIdx.x;

    if (blockIdx.x < 1024) {
        int b = blockIdx.x >> 5, cig = blockIdx.x & 31;
        int r = tid >> 3, c4 = (tid & 7) * 4;
        const float4* xv = (const float4*)(x + ((size_t)(b * 256 + cig * 8)) * 1024);
        #pragma unroll
        for (int u = 0; u < 8; ++u) {
            float4 v = xv[u * 256 + r * 8 + (c4 >> 2)];
            union { unsigned short s[4]; uint2 d; } pk;
            pk.s[0] = f2bf(v.x); pk.s[1] = f2bf(v.y);
            pk.s[2] = f2bf(v.z); pk.s[3] = f2bf(v.w);
            *(uint2*)&sh.tr[u * 1024 + r * 32 + c4] = pk.d;   // ds_write_b64
        }
        __syncthreads();
        uint4* dst = (uint4*)xb + ((size_t)b * 32 + cig) * 1024;
        #pragma unroll
        for (int k = 0; k < 4; ++k) {
            int g = k * 256 + tid;                            // lane-consecutive
            union { unsigned short u[8]; uint4 v; } pk;
            #pragma unroll
            for (int u = 0; u < 8; ++u) pk.u[u] = sh.tr[u * 1024 + g];
            dst[g] = pk.v;                                    // coalesced 1KB/wave
        }
        return;
    }

    int blk = blockIdx.x - 1024, lane = tid & 63;
    bool colmode = blk >= 256;
    int pc = blk & 255;
    if (tid < 45) sh.wm.sdata[tid] = 0.f;

    int p = colmode ? tid : pc;
    int c = colmode ? pc : tid;
    float w9[9];
    #pragma unroll
    for (int t = 0; t < 9; ++t) w9[t] = w[(p * 256 + c) * 9 + t];
    if (!colmode) {
        #pragma unroll
        for (int t = 0; t < 9; ++t) sh.wm.ws2[tid * 9 + t] = w9[t];
    }
    __syncthreads();

    int idx = 0;
    for (int ta = 0; ta < 9; ++ta)
        for (int tb = ta; tb < 9; ++tb) {
            float v = w9[ta] * w9[tb];
            #pragma unroll
            for (int off = 32; off > 0; off >>= 1) v += __shfl_down(v, off);
            if (lane == 0) atomicAdd(&sh.wm.sdata[idx], v);
            ++idx;
        }
    __syncthreads();
    if (tid < 45) (colmode ? Dcol : Drow)[tid * 256 + pc] = sh.wm.sdata[tid];

    if (!colmode) {
        // wt granule layout [t][ci>>3][co][ci&7]; this block covers co=p, all ci
        #pragma unroll
        for (int t = 0; t < 9; ++t)
            wt[t * 65536 + (c >> 3) * 2048 + p * 8 + (c & 7)] = f2bf(w9[t]);
        // Vb granules [row=p*10+ta][cig 32][8ci], tap slot 9 zeroed
        if (tid < 320) {
            int ta = tid >> 5, cig = tid & 31;
            union { unsigned short u[8]; uint4 v; } pk;
            #pragma unroll
            for (int u = 0; u < 8; ++u)
                pk.u[u] = (ta < 9) ? f2bf(sh.wm.ws2[(cig * 8 + u) * 9 + ta]) : (unsigned short)0;
            ((uint4*)Vb)[(p * 10 + ta) * 32 + cig] = pk.v;
        }
    }
}

// ---------------------------------------------------------------------------
// K1 — 128-thread (2-wave) blocks for max block-level TLP.
//  blocks 0..1023: conv, 32co x 8r per block (per wave: 32co x 4r, acc[1][4]).
//    R8 PMC closed the model: steady state was 2 conv blocks/CU (Occupancy
//    20%), and 2 x 36 MFMA x 32cy / 4 SIMD / 6800cy period = the measured
//    36% MfmaUtil. Pipe demand (matrix 2304, LDS ~3200, VALU 800 cyc/kc/CU)
//    says ~3200 is reachable with enough INDEPENDENT streams. This shape
//    gives 5 blocks/CU (LDS 28672 B) = 4-5 independent 2-wave pipelines.
//  Staging/counted-vmcnt skeleton = R4's proven pattern resized:
//    per wave/kc: stage_w 5|4 g2l16 (dbuf), stage_x 5 (single buf),
//    WAITV(5|4) retires prev kc's {w,x}, keeps w(kc+1) in flight.
//  Compute mapping = R1's verified wv*4+s, ns=s-atv, acc[ns].
//  blocks 1024..1433: Gram G = V V^T — 820 single-wave 64x64 upper tiles,
//    2 tiles/block via wv; appended last (short stragglers backfill).
// ---------------------------------------------------------------------------
__global__ __launch_bounds__(128, 3) void k_conv(const unsigned short* __restrict__ xb,
                                                 const unsigned short* __restrict__ wt,
                                                 const float* __restrict__ bias,
                                                 const unsigned short* __restrict__ Vb,
                                                 unsigned short* __restrict__ Gb,
                                                 float* __restrict__ y) {
    __shared__ unsigned short xs[640 * 8];     // [slot 10][cig 2][col 32][8ci] 10240 B
    __shared__ unsigned short wsm[2][576 * 8]; // [t 9][cig 2][co 32][8ci]    2x9216 B

    const int tid  = threadIdx.x;
    const int wv   = tid >> 6;               // wave 0..1
    const int lane = tid & 63;
    const int half = lane >> 5;
    const int m    = lane & 31;

    if (blockIdx.x >= 1024) {
        // ------- Gram path: 2 independent 64x64 upper tiles per block -------
        int tile = (blockIdx.x - 1024) * 2 + wv;     // 0..819
        int I = 0;
        while (tile >= 40 - I) { tile -= 40 - I; ++I; }
        int J = I + tile;
        const int row0 = I * 64;
        const int col0 = J * 64;

        float16 acc[2][2];
        #pragma unroll
        for (int i = 0; i < 2; ++i)
            #pragma unroll
            for (int j = 0; j < 2; ++j)
                #pragma unroll
                for (int r = 0; r < 16; ++r) acc[i][j][r] = 0.f;

        const short8* vb = (const short8*)Vb;
        for (int kc = 0; kc < 16; ++kc) {
            int cig = kc * 2 + half;
            short8 a0 = vb[(row0 + m) * 32 + cig];
            short8 a1 = vb[(row0 + 32 + m) * 32 + cig];
            short8 b0 = vb[(col0 + m) * 32 + cig];
            short8 b1 = vb[(col0 + 32 + m) * 32 + cig];
            acc[0][0] = __builtin_amdgcn_mfma_f32_32x32x16_bf16(a0, b0, acc[0][0], 0, 0, 0);
            acc[0][1] = __builtin_amdgcn_mfma_f32_32x32x16_bf16(a0, b1, acc[0][1], 0, 0, 0);
            acc[1][0] = __builtin_amdgcn_mfma_f32_32x32x16_bf16(a1, b0, acc[1][0], 0, 0, 0);
            acc[1][1] = __builtin_amdgcn_mfma_f32_32x32x16_bf16(a1, b1, acc[1][1], 0, 0, 0);
        }
        #pragma unroll
        for (int i = 0; i < 2; ++i)
            #pragma unroll
            for (int j = 0; j < 2; ++j)
                #pragma unroll
                for (int reg = 0; reg < 16; ++reg) {
                    int crow = (reg & 3) + 8 * (reg >> 2) + 4 * half;
                    Gb[(row0 + i * 32 + crow) * 2560 + col0 + j * 32 + m] =
                        f2bf(acc[i][j][reg]);
                }
        return;
    }

    // ---------------- conv path: 32co x 8r, 2 waves ----------------
    const int id    = blockIdx.x;            // 0..1023
    const int xcd   = id & 7;                // same-b blocks grouped per XCD L2
    const int local = id >> 3;               // 0..127
    const int b     = xcd * 4 + (local >> 5);
    const int rem   = local & 31;
    const int co0   = (rem & 7) * 32;
    const int r0    = (rem >> 3) * 8;

    float16 acc[4];                          // per wave: 32co x 4 rows
    #pragma unroll
    for (int ns = 0; ns < 4; ++ns)
        #pragma unroll
        for (int r = 0; r < 16; ++r) acc[ns][r] = 0.f;

    const uint4* xbv = (const uint4*)xb;
    const uint4* wtv = (const uint4*)wt;

    const int cigl = lane >> 5;              // staging: lane -> (cig, col/co)
    const int coll = lane & 31;

    // x: 10 slot-rows per kc into the SINGLE xs buffer; 5/5 per wave
    auto stage_x = [&](int kc) {
        uint4* xd = (uint4*)xs;
        #pragma unroll
        for (int ch = wv; ch < 10; ch += 2) {
            int gr = (r0 + ch + 31) & 31;               // rows r0-1 .. r0+8
            g2l16(&xbv[((b * 32 + kc * 2 + cigl) * 32 + gr) * 32 + coll],
                  &xd[ch * 64]);
        }
    };
    // w: 9 tap-rows per kc into wsm[buf]; 5/4 per wave
    auto stage_w = [&](int buf, int kc) {
        uint4* wd = (uint4*)wsm[buf];
        #pragma unroll
        for (int t = wv; t < 9; t += 2) {
            g2l16(&wtv[t * 8192 + (kc * 2 + cigl) * 256 + co0 + coll],
                  &wd[t * 64]);
        }
    };

    // btv-major: per btv 6 b-frags + 3 a-frags; 27 ds_read / 36 MFMA per kc.
    auto compute = [&](int buf) {
        const short8* xsl = (const short8*)xs;
        const short8* wsl = (const short8*)wsm[buf];
        #pragma unroll
        for (int btv = 0; btv < 3; ++btv) {
            int gc = (m + btv + 31) & 31;
            short8 a[3];
            #pragma unroll
            for (int atv = 0; atv < 3; ++atv)
                a[atv] = wsl[((atv * 3 + btv) * 2 + half) * 32 + m];
            #pragma unroll
            for (int s = 0; s < 6; ++s) {
                short8 bf = xsl[((wv * 4 + s) * 2 + half) * 32 + gc];
                #pragma unroll
                for (int atv = 0; atv < 3; ++atv) {
                    int ns = s - atv;
                    if (ns >= 0 && ns < 4)
                        acc[ns] = __builtin_amdgcn_mfma_f32_32x32x16_bf16(
                            a[atv], bf, acc[ns], 0, 0, 0);
                }
            }
        }
    };

    // Per-wave VMEM stream (vmcnt retires in order), steady state iter kc:
    //   ... w(kc)[5|4], x(kc)[5], w(kc+1)[5|4], WAITV(5|4) -> retires through
    //   x(kc); w(kc+1) stays in flight under compute(kc). Post-compute SBAR
    //   frees xs; x(kc+1) issued after it.
    stage_w(0, 0);
    stage_x(0);
    #pragma unroll 1
    for (int kc = 0; kc < 16; ++kc) {
        int buf = kc & 1;
        if (kc < 15) {
            stage_w(buf ^ 1, kc + 1);
            if (wv == 0) { WAITV(5); } else { WAITV(4); }
        } else {
            WAITV(0);
        }
        SBAR();                              // x(kc), w(kc) visible to both waves
        __builtin_amdgcn_s_setprio(1);
        compute(buf);
        __builtin_amdgcn_s_setprio(0);
        SBAR();                              // both waves done reading xs, wsm[buf]
        if (kc < 15) stage_x(kc + 1);
    }

    // epilogue: C layout: col=lane&31, row(co)=(reg&3)+8*(reg>>2)+4*half
    #pragma unroll
    for (int ns = 0; ns < 4; ++ns) {
        int r = r0 + wv * 4 + ns;
        #pragma unroll
        for (int reg = 0; reg < 16; ++reg) {
            int crow = (reg & 3) + 8 * (reg >> 2) + 4 * half;
            int co = co0 + crow;
            y[(b * 256 + co) * 1024 + r * 32 + m] = acc[ns][reg] + bias[co];
        }
    }
}

// ---------------------------------------------------------------------------
// K_loss: blocks 0..543 = Row/Col loss per bin; blocks 544..799 = AngLoss.
// Per-block partial sums stored to rowp/colp/angp — NO global atomics.
// D arrays are [coef 45][pc 256] so per-i loads are lane-coalesced.
// ---------------------------------------------------------------------------
__global__ __launch_bounds__(256) void k_loss(const float* __restrict__ Drow,
                                              const float* __restrict__ Dcol,
                                              const unsigned short* __restrict__ Gb,
                                              float* __restrict__ rowp,
                                              float* __restrict__ colp,
                                              float* __restrict__ angp) {
    __shared__ union {
        struct { float coef[45]; float red[2]; } rc;
        struct { unsigned short gs[9 * 2560]; float red; } ang;
    } sh;
    int tid = threadIdx.x;

    if (blockIdx.x < 544) {
        int bin = blockIdx.x;
        int u = bin / 17, v = bin % 17;
        if (tid < 2) sh.rc.red[tid] = 0.f;
        if (tid < 45) {
            int idx = 0, TA = 0, TB = 0;
            for (int ta = 0; ta < 9; ++ta)
                for (int tb = ta; tb < 9; ++tb) {
                    if (idx == tid) { TA = ta; TB = tb; }
                    ++idx;
                }
            int da = TA / 3 - TB / 3;
            int db = TA % 3 - TB % 3;
            float cth = cosf(TWO_PI_OVER_32 * (float)(u * da + v * db));
            sh.rc.coef[tid] = (TA == TB) ? 1.f : 2.f * cth;
        }
        __syncthreads();

        float s1 = 0.f, s2 = 0.f;
        const float* dr = Drow + tid;
        const float* dc = Dcol + tid;
        #pragma unroll
        for (int i = 0; i < 45; ++i) {
            s1 += sh.rc.coef[i] * dr[i * 256];
            s2 += sh.rc.coef[i] * dc[i * 256];
        }
        float e1 = sqrtf(fmaxf(s1, 0.f)) - 1.f; e1 *= e1;
        float e2 = sqrtf(fmaxf(s2, 0.f)) - 1.f; e2 *= e2;
        #pragma unroll
        for (int off = 32; off > 0; off >>= 1) {
            e1 += __shfl_down(e1, off);
            e2 += __shfl_down(e2, off);
        }
        if ((tid & 63) == 0) { atomicAdd(&sh.rc.red[0], e1); atomicAdd(&sh.rc.red[1], e2); }
        __syncthreads();
        if (tid == 0) { rowp[bin] = sh.rc.red[0]; colp[bin] = sh.rc.red[1]; }
    } else {
        int p = blockIdx.x - 544;
        if (tid == 0) sh.ang.red = 0.f;
        uint4* gsv = (uint4*)sh.ang.gs;
        const uint4* gbv = (const uint4*)Gb;
        for (int i = tid; i < 2880; i += 256) {
            int rr = i / 320, cc = i - rr * 320;
            gsv[i] = gbv[(p * 10 + rr) * 320 + cc];
        }
        __syncthreads();

        int q = tid;
        float S = 0.f;
        if (q > p) {
            float g5[5][5];
            #pragma unroll
            for (int i = 0; i < 5; ++i)
                #pragma unroll
                for (int j = 0; j < 5; ++j) g5[i][j] = 0.f;
            #pragma unroll
            for (int ta = 0; ta < 9; ++ta)
                #pragma unroll
                for (int tb = 0; tb < 9; ++tb) {
                    float c = bf2f(sh.ang.gs[ta * 2560 + q * 10 + tb]);
                    g5[ta / 3 - tb / 3 + 2][ta % 3 - tb % 3 + 2] += c;
                }
            // ReS = {17,0,1,0,1}
            #pragma unroll
            for (int da = 0; da < 5; ++da) {
                const float* g = g5[da];
                float sq = g[0]*g[0] + g[1]*g[1] + g[2]*g[2] + g[3]*g[3] + g[4]*g[4];
                float cr = g[0]*g[2] + g[1]*g[3] + g[2]*g[4] + g[0]*g[4];
                S += 17.f * sq + 2.f * cr;
            }
            S *= 32.f;
        }
        #pragma unroll
        for (int off = 32; off > 0; off >>= 1) S += __shfl_down(S, off);
        if ((tid & 63) == 0) atomicAdd(&sh.ang.red, S);
        __syncthreads();
        if (tid == 0) angp[p] = sh.ang.red;
    }
}

// ---------------------------------------------------------------------------
// K5: finalize L — reduce the per-block partials.
// ---------------------------------------------------------------------------
__global__ __launch_bounds__(256) void k_fin(const float* __restrict__ rowp,
                                             const float* __restrict__ colp,
                                             const float* __restrict__ angp,
                                             float* __restrict__ out) {
    __shared__ float sred[3][4];
    int tid = threadIdx.x;
    float r = 0.f, c = 0.f, a = 0.f;
    for (int i = tid; i < 544; i += 256) { r += rowp[i]; c += colp[i]; }
    a = angp[tid];
    #pragma unroll
    for (int off = 32; off > 0; off >>= 1) {
        r += __shfl_down(r, off);
        c += __shfl_down(c, off);
        a += __shfl_down(a, off);
    }
    if ((tid & 63) == 0) {
        int wv = tid >> 6;
        sred[0][wv] = r; sred[1][wv] = c; sred[2][wv] = a;
    }
    __syncthreads();
    if (tid == 0) {
        float R = sred[0][0] + sred[0][1] + sred[0][2] + sred[0][3];
        float C = sred[1][0] + sred[1][1] + sred[1][2] + sred[1][3];
        float A = sred[2][0] + sred[2][1] + sred[2][2] + sred[2][3];
        out[8388608] = R / 544.f + C / 544.f + A / (544.f * 32640.f);
    }
}

// ---------------------------------------------------------------------------
extern "C" void kernel_launch(void* const* d_in, const int* in_sizes, int n_in,
                              void* d_out, int out_size, void* d_ws, size_t ws_size,
                              hipStream_t stream) {
    const float* x    = (const float*)d_in[0];   // (32,256,32,32)
    const float* w    = (const float*)d_in[1];   // (256,256,3,3)
    const float* bias = (const float*)d_in[2];   // (256,)
    float* out = (float*)d_out;

    char* ws = (char*)d_ws;
    unsigned short* wt = (unsigned short*)ws;               //  1,179,648 B
    unsigned short* xb = (unsigned short*)(ws + 1179648);   // 16,777,216 B
    unsigned short* Vb = (unsigned short*)(ws + 17956864);  //  1,310,720 B
    float* Drow  = (float*)(ws + 19267584);                 //     46,080 B
    float* Dcol  = (float*)(ws + 19313664);                 //     46,080 B
    float* rowp  = (float*)(ws + 19359744);                 //      2,176 B
    float* colp  = (float*)(ws + 19361920);                 //      2,176 B
    float* angp  = (float*)(ws + 19364096);                 //      1,024 B
    unsigned short* Gb = (unsigned short*)(ws + 19392512);  // 13,107,200 B

    k_prepx <<<1536, 256, 0, stream>>>(x, xb, w, wt, Vb, Drow, Dcol);
    k_conv  <<<1434, 128, 0, stream>>>(xb, wt, bias, Vb, Gb, out);
    k_loss  <<<800, 256, 0, stream>>>(Drow, Dcol, Gb, rowp, colp, angp);
    k_fin   <<<1, 256, 0, stream>>>(rowp, colp, angp, out);
}

// Round 10
// 154.554 us; speedup vs baseline: 1.0058x; 1.0058x over previous
//
#include <hip/hip_runtime.h>
#include <math.h>

typedef __attribute__((ext_vector_type(8)))  short  short8;
typedef __attribute__((ext_vector_type(16))) float  float16;

#define TWO_PI_OVER_32 0.19634954084936207f

static __device__ __forceinline__ unsigned short f2bf(float f) {
    unsigned int u = __float_as_uint(f);
    u = (u + 0x7FFFu + ((u >> 16) & 1u)) >> 16;
    return (unsigned short)u;
}
static __device__ __forceinline__ float bf2f(unsigned short s) {
    return __uint_as_float(((unsigned int)s) << 16);
}

// async global->LDS 16B: per-lane global src, wave-uniform LDS base + lane*16
static __device__ __forceinline__ void g2l16(const void* g, void* l) {
    __builtin_amdgcn_global_load_lds(
        (const __attribute__((address_space(1))) unsigned int*)g,
        (__attribute__((address_space(3))) unsigned int*)l, 16, 0, 0);
}

// raw barrier + compiler-motion fence (no vmcnt drain, unlike __syncthreads)
#define SBAR() do { __builtin_amdgcn_s_barrier(); \
                    __builtin_amdgcn_sched_barrier(0); } while (0)
// counted vmcnt: retire oldest loads, keep newest N in flight across barriers
#define WAITV(n) do { asm volatile("s_waitcnt vmcnt(" #n ")" ::: "memory"); \
                      __builtin_amdgcn_sched_barrier(0); } while (0)
#define WAITLGKM0() do { asm volatile("s_waitcnt lgkmcnt(0)" ::: "memory"); \
                         __builtin_amdgcn_sched_barrier(0); } while (0)
#define SCHED_FENCE() __builtin_amdgcn_sched_barrier(0)

// ---------------------------------------------------------------------------
// K_prepx — weight-side only (the x-pass is FUSED into k_conv this round):
//  blocks 0..255 (row mode, p): Drow[45][256]; wt bf16 granules; Vb bf16
//  blocks 256..511 (col mode, c): Dcol[45][256]
// ---------------------------------------------------------------------------
__global__ __launch_bounds__(256) void k_prepx(const float* __restrict__ w,
                                               unsigned short* __restrict__ wt,
                                               unsigned short* __restrict__ Vb,
                                               float* __restrict__ Drow,
                                               float* __restrict__ Dcol) {
    __shared__ float sdata[45];
    __shared__ float ws2[256 * 9];
    int tid = threadIdx.x;
    int blk = blockIdx.x, lane = tid & 63;
    bool colmode = blk >= 256;
    int pc = blk & 255;
    if (tid < 45) sdata[tid] = 0.f;

    int p = colmode ? tid : pc;
    int c = colmode ? pc : tid;
    float w9[9];
    #pragma unroll
    for (int t = 0; t < 9; ++t) w9[t] = w[(p * 256 + c) * 9 + t];
    if (!colmode) {
        #pragma unroll
        for (int t = 0; t < 9; ++t) ws2[tid * 9 + t] = w9[t];
    }
    __syncthreads();

    int idx = 0;
    for (int ta = 0; ta < 9; ++ta)
        for (int tb = ta; tb < 9; ++tb) {
            float v = w9[ta] * w9[tb];
            #pragma unroll
            for (int off = 32; off > 0; off >>= 1) v += __shfl_down(v, off);
            if (lane == 0) atomicAdd(&sdata[idx], v);
            ++idx;
        }
    __syncthreads();
    if (tid < 45) (colmode ? Dcol : Drow)[tid * 256 + pc] = sdata[tid];

    if (!colmode) {
        // wt granule layout [t][ci>>3][co][ci&7]; this block covers co=p, all ci
        #pragma unroll
        for (int t = 0; t < 9; ++t)
            wt[t * 65536 + (c >> 3) * 2048 + p * 8 + (c & 7)] = f2bf(w9[t]);
        // Vb granules [row=p*10+ta][cig 32][8ci], tap slot 9 zeroed
        if (tid < 320) {
            int ta = tid >> 5, cig = tid & 31;
            union { unsigned short u[8]; uint4 v; } pk;
            #pragma unroll
            for (int u = 0; u < 8; ++u)
                pk.u[u] = (ta < 9) ? f2bf(ws2[(cig * 8 + u) * 9 + ta]) : (unsigned short)0;
            ((uint4*)Vb)[(p * 10 + ta) * 32 + cig] = pk.v;
        }
    }
}

// ---------------------------------------------------------------------------
// K1: blocks 0..209: Gram G = V V^T (upper tiles, first for co-scheduling).
//     blocks 210..721: conv, 64co x 8r, 4 waves, 3 blocks/CU (R4 skeleton).
// FUSED x staging: no xb intermediate. Per kc each block reg-stages its
//   20 KB fp32 x-slab (issue-early float4 loads -> f2bf pack -> ds_write_b32
//   after the xs-free barrier = T14 split). The 4 co-twin blocks are
//   dispatch-adjacent -> L2 absorbs the co-duplication; x is L3-resident
//   across iterations. Removes prepx's serial 144 MB HBM pass + conv's
//   17 MB xb fetch.
// Counted vmcnt (per-wave VMEM stream, sched-fenced so order is exact):
//   iter kc: xload(kc+1)[6|6|4|4] , stage_w(kc+1)[5|5|4|4] ->
//   WAITV(11|11|8|8) retires w(kc) exactly. cvt_x at iter end waits only
//   the xloads (older) leaving w(kc+1) in flight under compute(kc+1).
// LDS = xs 10240 (single) + wsm 2x18432 = 47104 B.
// ---------------------------------------------------------------------------
__global__ __launch_bounds__(256, 3) void k_conv(const float* __restrict__ xf,
                                                 const unsigned short* __restrict__ wt,
                                                 const float* __restrict__ bias,
                                                 const unsigned short* __restrict__ Vb,
                                                 unsigned short* __restrict__ Gb,
                                                 float* __restrict__ y) {
    __shared__ unsigned short xs[640 * 8];      // [slot 10][cig 2][col 32][8ci] 10240 B
    __shared__ unsigned short wsm[2][1152 * 8]; // [t 9][cig 2][co 64][8ci]   2x18432 B

    const int tid  = threadIdx.x;
    const int lane = tid & 63;
    const int half = lane >> 5;
    const int m    = lane & 31;

    if (blockIdx.x < 210) {
        // ---------------- Gram path ----------------
        int blk = blockIdx.x, I = 0;
        while (blk >= 20 - I) { blk -= 20 - I; ++I; }
        int J = I + blk;
        const int wave = tid >> 6;
        const int wm = wave >> 1, wn = wave & 1;
        const int row0 = I * 128 + wm * 64;
        const int col0 = J * 128 + wn * 64;

        float16 acc[2][2];
        #pragma unroll
        for (int i = 0; i < 2; ++i)
            #pragma unroll
            for (int j = 0; j < 2; ++j)
                #pragma unroll
                for (int r = 0; r < 16; ++r) acc[i][j][r] = 0.f;

        const short8* vb = (const short8*)Vb;
        for (int kc = 0; kc < 16; ++kc) {
            int cig = kc * 2 + half;
            short8 a0 = vb[(row0 + m) * 32 + cig];
            short8 a1 = vb[(row0 + 32 + m) * 32 + cig];
            short8 b0 = vb[(col0 + m) * 32 + cig];
            short8 b1 = vb[(col0 + 32 + m) * 32 + cig];
            acc[0][0] = __builtin_amdgcn_mfma_f32_32x32x16_bf16(a0, b0, acc[0][0], 0, 0, 0);
            acc[0][1] = __builtin_amdgcn_mfma_f32_32x32x16_bf16(a0, b1, acc[0][1], 0, 0, 0);
            acc[1][0] = __builtin_amdgcn_mfma_f32_32x32x16_bf16(a1, b0, acc[1][0], 0, 0, 0);
            acc[1][1] = __builtin_amdgcn_mfma_f32_32x32x16_bf16(a1, b1, acc[1][1], 0, 0, 0);
        }
        #pragma unroll
        for (int i = 0; i < 2; ++i)
            #pragma unroll
            for (int j = 0; j < 2; ++j)
                #pragma unroll
                for (int reg = 0; reg < 16; ++reg) {
                    int crow = (reg & 3) + 8 * (reg >> 2) + 4 * half;
                    Gb[(row0 + i * 32 + crow) * 2560 + col0 + j * 32 + m] =
                        f2bf(acc[i][j][reg]);
                }
        return;
    }

    // ---------------- conv path ----------------
    const int wv    = tid >> 6;              // wave 0..3
    const int id    = blockIdx.x - 210;      // 0..511
    const int xcd   = id & 7;                // same-b blocks grouped per XCD L2
    const int local = id >> 3;               // 0..63
    const int b     = xcd * 4 + (local >> 4);
    const int rem   = local & 15;
    const int co0   = (rem & 3) * 64;        // co-twins adjacent in dispatch
    const int r0    = (rem >> 2) * 8;

    float16 acc[2][2];
    #pragma unroll
    for (int i = 0; i < 2; ++i)
        #pragma unroll
        for (int ns = 0; ns < 2; ++ns)
            #pragma unroll
            for (int r = 0; r < 16; ++r) acc[i][ns][r] = 0.f;

    const uint4* wtv = (const uint4*)wt;

    const int cigl = lane >> 5;              // w staging: lane -> (cig, co)
    const int cnt  = (tid < 128) ? 3 : 2;    // x items per thread (waves 0,1 : 3)

    // w: 18 granule-rows per kc into wsm[buf]; 5/5/4/4 per wave
    auto stage_w = [&](int buf, int kc) {
        uint4* wd = (uint4*)wsm[buf];
        #pragma unroll
        for (int wc = wv; wc < 18; wc += 4) {
            int t = wc >> 1, cig = wc & 1;
            g2l16(&wtv[t * 8192 + (kc * 2 + cig) * 256 + co0 + lane],
                  &wd[wc * 64]);
        }
    };

    // x fused staging: 640 items (slot10, cig2, u2-pair4, c-quad8); thread j
    // item id = tid + 256*j (j<2) or 512+tid (j=2, tids<128).
    // Item: load float4 pair (ci = base+2*u2, base+2*u2+1) -> 8 floats.
    float4 xlo[3], xhi[3];
    auto load_x = [&](int kc) {
        #pragma unroll
        for (int j = 0; j < 3; ++j) {
            if (j < cnt) {
                int idg  = (j < 2) ? (tid + 256 * j) : (512 + tid);
                int slot = idg >> 6, sub = idg & 63;
                int cig  = sub >> 5, s32 = sub & 31;
                int u2   = s32 >> 3, cq = s32 & 7;
                int gr   = (r0 + slot + 31) & 31;
                const float* p = xf + ((size_t)(b * 256 + kc * 16 + cig * 8 + 2 * u2)) * 1024
                               + gr * 32 + cq * 4;
                xlo[j] = *(const float4*)p;
                xhi[j] = *(const float4*)(p + 1024);
            }
        }
    };
    // convert + write to xs (after xs-free barrier); compiler's vmcnt wait for
    // xlo/xhi leaves the newer w-g2l16 in flight.
    auto cvt_x = [&]() {
        unsigned int* xw = (unsigned int*)xs;
        #pragma unroll
        for (int j = 0; j < 3; ++j) {
            if (j < cnt) {
                int idg  = (j < 2) ? (tid + 256 * j) : (512 + tid);
                int slot = idg >> 6, sub = idg & 63;
                int cig  = sub >> 5, s32 = sub & 31;
                int u2   = s32 >> 3, cq = s32 & 7;
                const float* lp = (const float*)&xlo[j];
                const float* hp = (const float*)&xhi[j];
                #pragma unroll
                for (int e = 0; e < 4; ++e) {
                    unsigned int pk = (unsigned int)f2bf(lp[e]) |
                                      ((unsigned int)f2bf(hp[e]) << 16);
                    xw[((slot * 2 + cig) * 32 + cq * 4 + e) * 4 + u2] = pk;
                }
            }
        }
    };

    // btv-major compute: 30 ds_read_b128 / 36 MFMA per kc per wave.
    auto compute = [&](int buf) {
        const short8* xsl = (const short8*)xs;
        const short8* wsl = (const short8*)wsm[buf];
        #pragma unroll
        for (int btv = 0; btv < 3; ++btv) {
            short8 a0[3], a1[3];
            #pragma unroll
            for (int atv = 0; atv < 3; ++atv) {
                int t = atv * 3 + btv;
                a0[atv] = wsl[(t * 2 + half) * 64 + m];
                a1[atv] = wsl[(t * 2 + half) * 64 + 32 + m];
            }
            #pragma unroll
            for (int s = 0; s < 4; ++s) {
                short8 bf = xsl[((wv * 2 + s) * 2 + half) * 32 + ((m + btv + 31) & 31)];
                #pragma unroll
                for (int atv = 0; atv < 3; ++atv) {
                    int ns = s - atv;
                    if (ns >= 0 && ns < 2) {
                        acc[0][ns] = __builtin_amdgcn_mfma_f32_32x32x16_bf16(a0[atv], bf, acc[0][ns], 0, 0, 0);
                        acc[1][ns] = __builtin_amdgcn_mfma_f32_32x32x16_bf16(a1[atv], bf, acc[1][ns], 0, 0, 0);
                    }
                }
            }
        }
    };

    // Prologue: w(0) staged; x(0) loaded+converted (drains vmcnt incl. w(0) —
    // prologue only).
    stage_w(0, 0);
    SCHED_FENCE();
    load_x(0);
    SCHED_FENCE();
    cvt_x();
    #pragma unroll 1
    for (int kc = 0; kc < 16; ++kc) {
        int buf = kc & 1;
        if (kc < 15) {
            load_x(kc + 1);                  // issue early (T14): oldest in group
            SCHED_FENCE();
            stage_w(buf ^ 1, kc + 1);        // newer than xloads
            if (wv < 2) { WAITV(11); } else { WAITV(8); }   // retires w(kc)
        } else {
            WAITV(0);
        }
        WAITLGKM0();                         // xs(kc) ds_writes complete
        SBAR();                              // xs(kc), w(kc) visible to all
        __builtin_amdgcn_s_setprio(1);
        compute(buf);
        __builtin_amdgcn_s_setprio(0);
        SBAR();                              // all waves done reading xs
        if (kc < 15) cvt_x();                // waits xloads only; w stays in flight
    }

    // epilogue: C layout: col=lane&31, row=(reg&3)+8*(reg>>2)+4*half
    #pragma unroll
    for (int i = 0; i < 2; ++i) {
        #pragma unroll
        for (int ns = 0; ns < 2; ++ns) {
            int r = r0 + wv * 2 + ns;
            #pragma unroll
            for (int reg = 0; reg < 16; ++reg) {
                int crow = (reg & 3) + 8 * (reg >> 2) + 4 * half;
                int co = co0 + i * 32 + crow;
                y[(b * 256 + co) * 1024 + r * 32 + m] = acc[i][ns][reg] + bias[co];
            }
        }
    }
}

// ---------------------------------------------------------------------------
// K_loss: blocks 0..543 = Row/Col loss per bin; blocks 544..799 = AngLoss.
// Per-block partial sums stored to rowp/colp/angp — NO global atomics.
// D arrays are [coef 45][pc 256] so per-i loads are lane-coalesced.
// ---------------------------------------------------------------------------
__global__ __launch_bounds__(256) void k_loss(const float* __restrict__ Drow,
                                              const float* __restrict__ Dcol,
                                              const unsigned short* __restrict__ Gb,
                                              float* __restrict__ rowp,
                                              float* __restrict__ colp,
                                              float* __restrict__ angp) {
    __shared__ union {
        struct { float coef[45]; float red[2]; } rc;
        struct { unsigned short gs[9 * 2560]; float red; } ang;
    } sh;
    int tid = threadIdx.x;

    if (blockIdx.x < 544) {
        int bin = blockIdx.x;
        int u = bin / 17, v = bin % 17;
        if (tid < 2) sh.rc.red[tid] = 0.f;
        if (tid < 45) {
            int idx = 0, TA = 0, TB = 0;
            for (int ta = 0; ta < 9; ++ta)
                for (int tb = ta; tb < 9; ++tb) {
                    if (idx == tid) { TA = ta; TB = tb; }
                    ++idx;
                }
            int da = TA / 3 - TB / 3;
            int db = TA % 3 - TB % 3;
            float cth = cosf(TWO_PI_OVER_32 * (float)(u * da + v * db));
            sh.rc.coef[tid] = (TA == TB) ? 1.f : 2.f * cth;
        }
        __syncthreads();

        float s1 = 0.f, s2 = 0.f;
        const float* dr = Drow + tid;
        const float* dc = Dcol + tid;
        #pragma unroll
        for (int i = 0; i < 45; ++i) {
            s1 += sh.rc.coef[i] * dr[i * 256];
            s2 += sh.rc.coef[i] * dc[i * 256];
        }
        float e1 = sqrtf(fmaxf(s1, 0.f)) - 1.f; e1 *= e1;
        float e2 = sqrtf(fmaxf(s2, 0.f)) - 1.f; e2 *= e2;
        #pragma unroll
        for (int off = 32; off > 0; off >>= 1) {
            e1 += __shfl_down(e1, off);
            e2 += __shfl_down(e2, off);
        }
        if ((tid & 63) == 0) { atomicAdd(&sh.rc.red[0], e1); atomicAdd(&sh.rc.red[1], e2); }
        __syncthreads();
        if (tid == 0) { rowp[bin] = sh.rc.red[0]; colp[bin] = sh.rc.red[1]; }
    } else {
        int p = blockIdx.x - 544;
        if (tid == 0) sh.ang.red = 0.f;
        uint4* gsv = (uint4*)sh.ang.gs;
        const uint4* gbv = (const uint4*)Gb;
        for (int i = tid; i < 2880; i += 256) {
            int rr = i / 320, cc = i - rr * 320;
            gsv[i] = gbv[(p * 10 + rr) * 320 + cc];
        }
        __syncthreads();

        int q = tid;
        float S = 0.f;
        if (q > p) {
            float g5[5][5];
            #pragma unroll
            for (int i = 0; i < 5; ++i)
                #pragma unroll
                for (int j = 0; j < 5; ++j) g5[i][j] = 0.f;
            #pragma unroll
            for (int ta = 0; ta < 9; ++ta)
                #pragma unroll
                for (int tb = 0; tb < 9; ++tb) {
                    float c = bf2f(sh.ang.gs[ta * 2560 + q * 10 + tb]);
                    g5[ta / 3 - tb / 3 + 2][ta % 3 - tb % 3 + 2] += c;
                }
            // ReS = {17,0,1,0,1}
            #pragma unroll
            for (int da = 0; da < 5; ++da) {
                const float* g = g5[da];
                float sq = g[0]*g[0] + g[1]*g[1] + g[2]*g[2] + g[3]*g[3] + g[4]*g[4];
                float cr = g[0]*g[2] + g[1]*g[3] + g[2]*g[4] + g[0]*g[4];
                S += 17.f * sq + 2.f * cr;
            }
            S *= 32.f;
        }
        #pragma unroll
        for (int off = 32; off > 0; off >>= 1) S += __shfl_down(S, off);
        if ((tid & 63) == 0) atomicAdd(&sh.ang.red, S);
        __syncthreads();
        if (tid == 0) angp[p] = sh.ang.red;
    }
}

// ---------------------------------------------------------------------------
// K5: finalize L — reduce the per-block partials.
// ---------------------------------------------------------------------------
__global__ __launch_bounds__(256) void k_fin(const float* __restrict__ rowp,
                                             const float* __restrict__ colp,
                                             const float* __restrict__ angp,
                                             float* __restrict__ out) {
    __shared__ float sred[3][4];
    int tid = threadIdx.x;
    float r = 0.f, c = 0.f, a = 0.f;
    for (int i = tid; i < 544; i += 256) { r += rowp[i]; c += colp[i]; }
    a = angp[tid];
    #pragma unroll
    for (int off = 32; off > 0; off >>= 1) {
        r += __shfl_down(r, off);
        c += __shfl_down(c, off);
        a += __shfl_down(a, off);
    }
    if ((tid & 63) == 0) {
        int wv = tid >> 6;
        sred[0][wv] = r; sred[1][wv] = c; sred[2][wv] = a;
    }
    __syncthreads();
    if (tid == 0) {
        float R = sred[0][0] + sred[0][1] + sred[0][2] + sred[0][3];
        float C = sred[1][0] + sred[1][1] + sred[1][2] + sred[1][3];
        float A = sred[2][0] + sred[2][1] + sred[2][2] + sred[2][3];
        out[8388608] = R / 544.f + C / 544.f + A / (544.f * 32640.f);
    }
}

// ---------------------------------------------------------------------------
extern "C" void kernel_launch(void* const* d_in, const int* in_sizes, int n_in,
                              void* d_out, int out_size, void* d_ws, size_t ws_size,
                              hipStream_t stream) {
    const float* x    = (const float*)d_in[0];   // (32,256,32,32)
    const float* w    = (const float*)d_in[1];   // (256,256,3,3)
    const float* bias = (const float*)d_in[2];   // (256,)
    float* out = (float*)d_out;

    char* ws = (char*)d_ws;
    unsigned short* wt = (unsigned short*)ws;               //  1,179,648 B
    unsigned short* Vb = (unsigned short*)(ws + 1179648);   //  1,310,720 B
    float* Drow  = (float*)(ws + 2490368);                  //     46,080 B
    float* Dcol  = (float*)(ws + 2536448);                  //     46,080 B
    float* rowp  = (float*)(ws + 2582528);                  //      2,176 B
    float* colp  = (float*)(ws + 2584704);                  //      2,176 B
    float* angp  = (float*)(ws + 2586880);                  //      1,024 B
    unsigned short* Gb = (unsigned short*)(ws + 2588672);   // 13,107,200 B

    k_prepx <<<512, 256, 0, stream>>>(w, wt, Vb, Drow, Dcol);
    k_conv  <<<722, 256, 0, stream>>>(x, wt, bias, Vb, Gb, out);
    k_loss  <<<800, 256, 0, stream>>>(Drow, Dcol, Gb, rowp, colp, angp);
    k_fin   <<<1, 256, 0, stream>>>(rowp, colp, angp, out);
}

// Round 11
// 149.830 us; speedup vs baseline: 1.0375x; 1.0315x over previous
//
#include <hip/hip_runtime.h>
#include <math.h>

typedef __attribute__((ext_vector_type(8)))  short  short8;
typedef __attribute__((ext_vector_type(16))) float  float16;

#define TWO_PI_OVER_32 0.19634954084936207f

static __device__ __forceinline__ unsigned short f2bf(float f) {
    unsigned int u = __float_as_uint(f);
    u = (u + 0x7FFFu + ((u >> 16) & 1u)) >> 16;
    return (unsigned short)u;
}
static __device__ __forceinline__ float bf2f(unsigned short s) {
    return __uint_as_float(((unsigned int)s) << 16);
}

// async global->LDS 16B: per-lane global src, wave-uniform LDS base + lane*16
static __device__ __forceinline__ void g2l16(const void* g, void* l) {
    __builtin_amdgcn_global_load_lds(
        (const __attribute__((address_space(1))) unsigned int*)g,
        (__attribute__((address_space(3))) unsigned int*)l, 16, 0, 0);
}

// raw barrier + compiler-motion fence (no vmcnt drain, unlike __syncthreads)
#define SBAR() do { __builtin_amdgcn_s_barrier(); \
                    __builtin_amdgcn_sched_barrier(0); } while (0)
// counted vmcnt: retire oldest loads, keep newest N in flight across barriers
#define WAITV(n) do { asm volatile("s_waitcnt vmcnt(" #n ")" ::: "memory"); \
                      __builtin_amdgcn_sched_barrier(0); } while (0)

// ---------------------------------------------------------------------------
// K_prepx:
//  blocks 0..1023: x fp32 -> xb bf16 granules via LDS transpose, vectorized:
//    float4 coalesced loads -> f2bf -> LDS [u][r*32+c] -> coalesced uint4
//    granule stores (g = k*256+tid, lane-consecutive).
//  blocks 1024..1279 (row mode, p): Drow[45][256]; wt bf16 granules; Vb bf16
//  blocks 1280..1535 (col mode, c): Dcol[45][256]
// ---------------------------------------------------------------------------
__global__ __launch_bounds__(256) void k_prepx(const float* __restrict__ x,
                                               unsigned short* __restrict__ xb,
                                               const float* __restrict__ w,
                                               unsigned short* __restrict__ wt,
                                               unsigned short* __restrict__ Vb,
                                               float* __restrict__ Drow,
                                               float* __restrict__ Dcol) {
    __shared__ union {
        unsigned short tr[8 * 1024];             // [u][r*32+c] 16 KB
        struct { float sdata[45]; float ws2[256 * 9]; } wm;
    } sh;
    int tid = threadIdx.x;

    if (blockIdx.x < 1024) {
        int b = blockIdx.x >> 5, cig = blockIdx.x & 31;
        int r = tid >> 3, c4 = (tid & 7) * 4;
        const float4* xv = (const float4*)(x + ((size_t)(b * 256 + cig * 8)) * 1024);
        #pragma unroll
        for (int u = 0; u < 8; ++u) {
            float4 v = xv[u * 256 + r * 8 + (c4 >> 2)];
            union { unsigned short s[4]; uint2 d; } pk;
            pk.s[0] = f2bf(v.x); pk.s[1] = f2bf(v.y);
            pk.s[2] = f2bf(v.z); pk.s[3] = f2bf(v.w);
            *(uint2*)&sh.tr[u * 1024 + r * 32 + c4] = pk.d;   // ds_write_b64
        }
        __syncthreads();
        uint4* dst = (uint4*)xb + ((size_t)b * 32 + cig) * 1024;
        #pragma unroll
        for (int k = 0; k < 4; ++k) {
            int g = k * 256 + tid;                            // lane-consecutive
            union { unsigned short u[8]; uint4 v; } pk;
            #pragma unroll
            for (int u = 0; u < 8; ++u) pk.u[u] = sh.tr[u * 1024 + g];
            dst[g] = pk.v;                                    // coalesced 1KB/wave
        }
        return;
    }

    int blk = blockIdx.x - 1024, lane = tid & 63;
    bool colmode = blk >= 256;
    int pc = blk & 255;
    if (tid < 45) sh.wm.sdata[tid] = 0.f;

    int p = colmode ? tid : pc;
    int c = colmode ? pc : tid;
    float w9[9];
    #pragma unroll
    for (int t = 0; t < 9; ++t) w9[t] = w[(p * 256 + c) * 9 + t];
    if (!colmode) {
        #pragma unroll
        for (int t = 0; t < 9; ++t) sh.wm.ws2[tid * 9 + t] = w9[t];
    }
    __syncthreads();

    int idx = 0;
    for (int ta = 0; ta < 9; ++ta)
        for (int tb = ta; tb < 9; ++tb) {
            float v = w9[ta] * w9[tb];
            #pragma unroll
            for (int off = 32; off > 0; off >>= 1) v += __shfl_down(v, off);
            if (lane == 0) atomicAdd(&sh.wm.sdata[idx], v);
            ++idx;
        }
    __syncthreads();
    if (tid < 45) (colmode ? Dcol : Drow)[tid * 256 + pc] = sh.wm.sdata[tid];

    if (!colmode) {
        // wt granule layout [t][ci>>3][co][ci&7]; this block covers co=p, all ci
        #pragma unroll
        for (int t = 0; t < 9; ++t)
            wt[t * 65536 + (c >> 3) * 2048 + p * 8 + (c & 7)] = f2bf(w9[t]);
        // Vb granules [row=p*10+ta][cig 32][8ci], tap slot 9 zeroed
        if (tid < 320) {
            int ta = tid >> 5, cig = tid & 31;
            union { unsigned short u[8]; uint4 v; } pk;
            #pragma unroll
            for (int u = 0; u < 8; ++u)
                pk.u[u] = (ta < 9) ? f2bf(sh.wm.ws2[(cig * 8 + u) * 9 + ta]) : (unsigned short)0;
            ((uint4*)Vb)[(p * 10 + ta) * 32 + cig] = pk.v;
        }
    }
}

// ---------------------------------------------------------------------------
// K1 — EXACT R4 structure (best measured conv: 44.8 us).
//  blocks 0..209: Gram G = V V^T (2560x2560, K=256), upper tiles — first
//     so they co-schedule with conv from t=0.
//  blocks 210..721: conv via implicit GEMM, 64co x 8r per block.
// LDS = 10240 (x, SINGLE buffer) + 2x18432 (w, double buffer) = 47104 B
//   -> 3 blocks/CU; counted-vmcnt keeps w(kc+1) in flight under compute(kc).
// ---------------------------------------------------------------------------
__global__ __launch_bounds__(256, 3) void k_conv(const unsigned short* __restrict__ xb,
                                                 const unsigned short* __restrict__ wt,
                                                 const float* __restrict__ bias,
                                                 const unsigned short* __restrict__ Vb,
                                                 unsigned short* __restrict__ Gb,
                                                 float* __restrict__ y) {
    __shared__ unsigned short xs[640 * 8];      // [slot 10][cig 2][col 32][8ci] 10240 B
    __shared__ unsigned short wsm[2][1152 * 8]; // [t 9][cig 2][co 64][8ci]   2x18432 B

    const int tid  = threadIdx.x;
    const int lane = tid & 63;
    const int half = lane >> 5;
    const int m    = lane & 31;

    if (blockIdx.x < 210) {
        // ---------------- Gram path ----------------
        int blk = blockIdx.x, I = 0;
        while (blk >= 20 - I) { blk -= 20 - I; ++I; }
        int J = I + blk;
        const int wave = tid >> 6;
        const int wm = wave >> 1, wn = wave & 1;
        const int row0 = I * 128 + wm * 64;
        const int col0 = J * 128 + wn * 64;

        float16 acc[2][2];
        #pragma unroll
        for (int i = 0; i < 2; ++i)
            #pragma unroll
            for (int j = 0; j < 2; ++j)
                #pragma unroll
                for (int r = 0; r < 16; ++r) acc[i][j][r] = 0.f;

        const short8* vb = (const short8*)Vb;
        for (int kc = 0; kc < 16; ++kc) {
            int cig = kc * 2 + half;
            short8 a0 = vb[(row0 + m) * 32 + cig];
            short8 a1 = vb[(row0 + 32 + m) * 32 + cig];
            short8 b0 = vb[(col0 + m) * 32 + cig];
            short8 b1 = vb[(col0 + 32 + m) * 32 + cig];
            acc[0][0] = __builtin_amdgcn_mfma_f32_32x32x16_bf16(a0, b0, acc[0][0], 0, 0, 0);
            acc[0][1] = __builtin_amdgcn_mfma_f32_32x32x16_bf16(a0, b1, acc[0][1], 0, 0, 0);
            acc[1][0] = __builtin_amdgcn_mfma_f32_32x32x16_bf16(a1, b0, acc[1][0], 0, 0, 0);
            acc[1][1] = __builtin_amdgcn_mfma_f32_32x32x16_bf16(a1, b1, acc[1][1], 0, 0, 0);
        }
        #pragma unroll
        for (int i = 0; i < 2; ++i)
            #pragma unroll
            for (int j = 0; j < 2; ++j)
                #pragma unroll
                for (int reg = 0; reg < 16; ++reg) {
                    int crow = (reg & 3) + 8 * (reg >> 2) + 4 * half;
                    Gb[(row0 + i * 32 + crow) * 2560 + col0 + j * 32 + m] =
                        f2bf(acc[i][j][reg]);
                }
        return;
    }

    // ---------------- conv path ----------------
    const int wv    = tid >> 6;              // wave 0..3 -> row pair
    const int id    = blockIdx.x - 210;      // 0..511
    const int xcd   = id & 7;                // same-b blocks grouped per XCD L2
    const int local = id >> 3;               // 0..63
    const int b     = xcd * 4 + (local >> 4);
    const int rem   = local & 15;
    const int co0   = (rem & 3) * 64;
    const int r0    = (rem >> 2) * 8;

    float16 acc[2][2];
    #pragma unroll
    for (int i = 0; i < 2; ++i)
        #pragma unroll
        for (int ns = 0; ns < 2; ++ns)
            #pragma unroll
            for (int r = 0; r < 16; ++r) acc[i][ns][r] = 0.f;

    const uint4* xbv = (const uint4*)xb;
    const uint4* wtv = (const uint4*)wt;

    const int cigl = lane >> 5;              // x staging: lane -> (cig, col)
    const int coll = lane & 31;

    // x: 10 granule-rows per kc into the SINGLE xs buffer; 3/3/2/2 per wave
    auto stage_x = [&](int kc) {
        uint4* xd = (uint4*)xs;
        #pragma unroll
        for (int ch = wv; ch < 10; ch += 4) {
            int gr = (r0 + ch + 31) & 31;               // rows r0-1 .. r0+8
            g2l16(&xbv[((b * 32 + kc * 2 + cigl) * 32 + gr) * 32 + coll],
                  &xd[ch * 64]);
        }
    };
    // w: 18 granule-rows per kc into wsm[buf]; 5/5/4/4 per wave
    auto stage_w = [&](int buf, int kc) {
        uint4* wd = (uint4*)wsm[buf];
        #pragma unroll
        for (int wc = wv; wc < 18; wc += 4) {
            int t = wc >> 1, cig = wc & 1;
            g2l16(&wtv[t * 8192 + (kc * 2 + cig) * 256 + co0 + lane],
                  &wd[wc * 64]);
        }
    };

    // btv-major: each distinct (slot, btv) B fragment read once, reused across
    // valid (atv, ns) with ns = s - atv.  30 ds_read_b128 / 36 MFMA per kc.
    auto compute = [&](int buf) {
        const short8* xsl = (const short8*)xs;
        const short8* wsl = (const short8*)wsm[buf];
        #pragma unroll
        for (int btv = 0; btv < 3; ++btv) {
            short8 a0[3], a1[3];
            #pragma unroll
            for (int atv = 0; atv < 3; ++atv) {
                int t = atv * 3 + btv;
                a0[atv] = wsl[(t * 2 + half) * 64 + m];
                a1[atv] = wsl[(t * 2 + half) * 64 + 32 + m];
            }
            #pragma unroll
            for (int s = 0; s < 4; ++s) {
                short8 bf = xsl[((wv * 2 + s) * 2 + half) * 32 + ((m + btv + 31) & 31)];
                #pragma unroll
                for (int atv = 0; atv < 3; ++atv) {
                    int ns = s - atv;
                    if (ns >= 0 && ns < 2) {
                        acc[0][ns] = __builtin_amdgcn_mfma_f32_32x32x16_bf16(a0[atv], bf, acc[0][ns], 0, 0, 0);
                        acc[1][ns] = __builtin_amdgcn_mfma_f32_32x32x16_bf16(a1[atv], bf, acc[1][ns], 0, 0, 0);
                    }
                }
            }
        }
    };

    // Per-wave VMEM stream (vmcnt retires in order), steady state iter kc:
    //   ... w(kc)[5|4], x(kc)[3|2], w(kc+1)[5|4], WAITV(5|4)  -> retires
    //   through x(kc) (and w(kc)); w(kc+1) stays in flight under compute(kc).
    // Post-compute SBAR frees xs; x(kc+1) issued after it.
    stage_w(0, 0);
    stage_x(0);
    #pragma unroll 1
    for (int kc = 0; kc < 16; ++kc) {
        int buf = kc & 1;
        if (kc < 15) {
            stage_w(buf ^ 1, kc + 1);
            if (wv < 2) { WAITV(5); } else { WAITV(4); }
        } else {
            WAITV(0);
        }
        SBAR();                              // x(kc), w(kc) visible to all waves
        __builtin_amdgcn_s_setprio(1);
        compute(buf);
        __builtin_amdgcn_s_setprio(0);
        SBAR();                              // all waves done reading xs, wsm[buf]
        if (kc < 15) stage_x(kc + 1);
    }

    // epilogue: C layout: col=lane&31, row=(reg&3)+8*(reg>>2)+4*half
    #pragma unroll
    for (int i = 0; i < 2; ++i) {
        #pragma unroll
        for (int ns = 0; ns < 2; ++ns) {
            int r = r0 + wv * 2 + ns;
            #pragma unroll
            for (int reg = 0; reg < 16; ++reg) {
                int crow = (reg & 3) + 8 * (reg >> 2) + 4 * half;
                int co = co0 + i * 32 + crow;
                y[(b * 256 + co) * 1024 + r * 32 + m] = acc[i][ns][reg] + bias[co];
            }
        }
    }
}

// ---------------------------------------------------------------------------
// K_loss: blocks 0..543 = Row/Col loss per bin; blocks 544..799 = AngLoss.
// Per-block partial sums stored to rowp/colp/angp — NO global atomics.
// Ang trim: per-(q,ta) reads are 4x ds_read_b32 + 1 u16 (q*10 u16 offsets are
// 4B-aligned) instead of 9 scalar u16 reads — 37 vs 81 LDS instrs/thread.
// ---------------------------------------------------------------------------
__global__ __launch_bounds__(256) void k_loss(const float* __restrict__ Drow,
                                              const float* __restrict__ Dcol,
                                              const unsigned short* __restrict__ Gb,
                                              float* __restrict__ rowp,
                                              float* __restrict__ colp,
                                              float* __restrict__ angp) {
    __shared__ union {
        struct { float coef[45]; float red[2]; } rc;
        struct { unsigned short gs[9 * 2560]; float red; } ang;
    } sh;
    int tid = threadIdx.x;

    if (blockIdx.x < 544) {
        int bin = blockIdx.x;
        int u = bin / 17, v = bin % 17;
        if (tid < 2) sh.rc.red[tid] = 0.f;
        if (tid < 45) {
            int idx = 0, TA = 0, TB = 0;
            for (int ta = 0; ta < 9; ++ta)
                for (int tb = ta; tb < 9; ++tb) {
                    if (idx == tid) { TA = ta; TB = tb; }
                    ++idx;
                }
            int da = TA / 3 - TB / 3;
            int db = TA % 3 - TB % 3;
            float cth = cosf(TWO_PI_OVER_32 * (float)(u * da + v * db));
            sh.rc.coef[tid] = (TA == TB) ? 1.f : 2.f * cth;
        }
        __syncthreads();

        float s1 = 0.f, s2 = 0.f;
        const float* dr = Drow + tid;
        const float* dc = Dcol + tid;
        #pragma unroll
        for (int i = 0; i < 45; ++i) {
            s1 += sh.rc.coef[i] * dr[i * 256];
            s2 += sh.rc.coef[i] * dc[i * 256];
        }
        float e1 = sqrtf(fmaxf(s1, 0.f)) - 1.f; e1 *= e1;
        float e2 = sqrtf(fmaxf(s2, 0.f)) - 1.f; e2 *= e2;
        #pragma unroll
        for (int off = 32; off > 0; off >>= 1) {
            e1 += __shfl_down(e1, off);
            e2 += __shfl_down(e2, off);
        }
        if ((tid & 63) == 0) { atomicAdd(&sh.rc.red[0], e1); atomicAdd(&sh.rc.red[1], e2); }
        __syncthreads();
        if (tid == 0) { rowp[bin] = sh.rc.red[0]; colp[bin] = sh.rc.red[1]; }
    } else {
        int p = blockIdx.x - 544;
        if (tid == 0) sh.ang.red = 0.f;
        uint4* gsv = (uint4*)sh.ang.gs;
        const uint4* gbv = (const uint4*)Gb;
        for (int i = tid; i < 2880; i += 256) {
            int rr = i / 320, cc = i - rr * 320;
            gsv[i] = gbv[(p * 10 + rr) * 320 + cc];
        }
        __syncthreads();

        int q = tid;
        float S = 0.f;
        if (q > p) {
            float g5[5][5];
            #pragma unroll
            for (int i = 0; i < 5; ++i)
                #pragma unroll
                for (int j = 0; j < 5; ++j) g5[i][j] = 0.f;
            const unsigned int* gs32 = (const unsigned int*)sh.ang.gs;
            #pragma unroll
            for (int ta = 0; ta < 9; ++ta) {
                int b16 = ta * 2560 + q * 10;        // even -> u32-exact
                int b32 = b16 >> 1;
                float vv[9];
                #pragma unroll
                for (int j = 0; j < 4; ++j) {
                    unsigned int uu = gs32[b32 + j];
                    vv[2 * j]     = bf2f((unsigned short)(uu & 0xffffu));
                    vv[2 * j + 1] = bf2f((unsigned short)(uu >> 16));
                }
                vv[8] = bf2f(sh.ang.gs[b16 + 8]);
                #pragma unroll
                for (int tb = 0; tb < 9; ++tb)
                    g5[ta / 3 - tb / 3 + 2][ta % 3 - tb % 3 + 2] += vv[tb];
            }
            // ReS = {17,0,1,0,1}
            #pragma unroll
            for (int da = 0; da < 5; ++da) {
                const float* g = g5[da];
                float sq = g[0]*g[0] + g[1]*g[1] + g[2]*g[2] + g[3]*g[3] + g[4]*g[4];
                float cr = g[0]*g[2] + g[1]*g[3] + g[2]*g[4] + g[0]*g[4];
                S += 17.f * sq + 2.f * cr;
            }
            S *= 32.f;
        }
        #pragma unroll
        for (int off = 32; off > 0; off >>= 1) S += __shfl_down(S, off);
        if ((tid & 63) == 0) atomicAdd(&sh.ang.red, S);
        __syncthreads();
        if (tid == 0) angp[p] = sh.ang.red;
    }
}

// ---------------------------------------------------------------------------
// K5: finalize L — reduce the per-block partials.
// ---------------------------------------------------------------------------
__global__ __launch_bounds__(256) void k_fin(const float* __restrict__ rowp,
                                             const float* __restrict__ colp,
                                             const float* __restrict__ angp,
                                             float* __restrict__ out) {
    __shared__ float sred[3][4];
    int tid = threadIdx.x;
    float r = 0.f, c = 0.f, a = 0.f;
    for (int i = tid; i < 544; i += 256) { r += rowp[i]; c += colp[i]; }
    a = angp[tid];
    #pragma unroll
    for (int off = 32; off > 0; off >>= 1) {
        r += __shfl_down(r, off);
        c += __shfl_down(c, off);
        a += __shfl_down(a, off);
    }
    if ((tid & 63) == 0) {
        int wv = tid >> 6;
        sred[0][wv] = r; sred[1][wv] = c; sred[2][wv] = a;
    }
    __syncthreads();
    if (tid == 0) {
        float R = sred[0][0] + sred[0][1] + sred[0][2] + sred[0][3];
        float C = sred[1][0] + sred[1][1] + sred[1][2] + sred[1][3];
        float A = sred[2][0] + sred[2][1] + sred[2][2] + sred[2][3];
        out[8388608] = R / 544.f + C / 544.f + A / (544.f * 32640.f);
    }
}

// ---------------------------------------------------------------------------
extern "C" void kernel_launch(void* const* d_in, const int* in_sizes, int n_in,
                              void* d_out, int out_size, void* d_ws, size_t ws_size,
                              hipStream_t stream) {
    const float* x    = (const float*)d_in[0];   // (32,256,32,32)
    const float* w    = (const float*)d_in[1];   // (256,256,3,3)
    const float* bias = (const float*)d_in[2];   // (256,)
    float* out = (float*)d_out;

    char* ws = (char*)d_ws;
    unsigned short* wt = (unsigned short*)ws;               //  1,179,648 B
    unsigned short* xb = (unsigned short*)(ws + 1179648);   // 16,777,216 B
    unsigned short* Vb = (unsigned short*)(ws + 17956864);  //  1,310,720 B
    float* Drow  = (float*)(ws + 19267584);                 //     46,080 B
    float* Dcol  = (float*)(ws + 19313664);                 //     46,080 B
    float* rowp  = (float*)(ws + 19359744);                 //      2,176 B
    float* colp  = (float*)(ws + 19361920);                 //      2,176 B
    float* angp  = (float*)(ws + 19364096);                 //      1,024 B
    unsigned short* Gb = (unsigned short*)(ws + 19392512);  // 13,107,200 B

    k_prepx <<<1536, 256, 0, stream>>>(x, xb, w, wt, Vb, Drow, Dcol);
    k_conv  <<<722, 256, 0, stream>>>(xb, wt, bias, Vb, Gb, out);
    k_loss  <<<800, 256, 0, stream>>>(Drow, Dcol, Gb, rowp, colp, angp);
    k_fin   <<<1, 256, 0, stream>>>(rowp, colp, angp, out);
}